// Round 2
// baseline (391.783 us; speedup 1.0000x reference)
//
#include <hip/hip_runtime.h>

// Problem constants
#define B_SZ  4
#define C_IN  256
#define N_POS 4096     // H*W = 64*64
#define NH    2
#define HC    64       // hidden per head

typedef __attribute__((ext_vector_type(8))) __bf16 bf16x8;
typedef __attribute__((ext_vector_type(4))) float  f32x4;
typedef unsigned short u16;

__device__ __forceinline__ u16 f2bf(float f) {
  unsigned u = __float_as_uint(f);
  u = u + 0x7FFF + ((u >> 16) & 1);   // round-nearest-even
  return (u16)(u >> 16);
}

// v_exp_f32 computes 2^x. Prefer a builtin if present, else libm exp2f.
#if __has_builtin(__builtin_amdgcn_exp2f)
  #define EXP2(x) __builtin_amdgcn_exp2f(x)
#else
  #define EXP2(x) exp2f(x)
#endif

// packed f32x2 -> bf16x2 (RNE), low half = src0
__device__ __forceinline__ unsigned cvtpk_bf16(float lo, float hi) {
  unsigned r;
  asm("v_cvt_pk_bf16_f32 %0, %1, %2" : "=v"(r) : "v"(lo), "v"(hi));
  return r;
}

// ---------------------------------------------------------------------------
// Kernel 0a: x [B][C][N] fp32  ->  x_t [B][N][C] bf16  (transposed cast)
// ---------------------------------------------------------------------------
__global__ __launch_bounds__(256) void k_prep_x(const float* __restrict__ x,
                                                u16* __restrict__ xt) {
  __shared__ float tile[32][33];
  int b = blockIdx.z, c0 = blockIdx.y * 32, n0 = blockIdx.x * 32;
  int tx = threadIdx.x, ty = threadIdx.y;   // (32, 8)
  const float* src = x + ((size_t)b * C_IN + c0) * N_POS + n0;
#pragma unroll
  for (int i = 0; i < 4; i++) tile[ty + 8*i][tx] = src[(size_t)(ty + 8*i) * N_POS + tx];
  __syncthreads();
  u16* dst = xt + ((size_t)b * N_POS + n0) * C_IN + c0;
#pragma unroll
  for (int i = 0; i < 4; i++) dst[(size_t)(ty + 8*i) * C_IN + tx] = f2bf(tile[tx][ty + 8*i]);
}

// ---------------------------------------------------------------------------
// Kernel 0b: cast embed_w -> wbf [384][256] bf16 ; transpose out_w -> w2t [256][128] bf16
// ---------------------------------------------------------------------------
__global__ __launch_bounds__(256) void k_prep_w(const float* __restrict__ ew,
                                                const float* __restrict__ ow,
                                                u16* __restrict__ wbf,
                                                u16* __restrict__ w2t) {
  int i = blockIdx.x * 256 + threadIdx.x;
  if (i < 384 * 256) wbf[i] = f2bf(ew[i]);
  if (i < 128 * 256) {
    int d = i >> 8, c = i & 255;              // out_w[d][c]
    w2t[c * 128 + d] = f2bf(ow[i]);
  }
}

// ---------------------------------------------------------------------------
// Kernel 1: QKV projection.  qkv[m][n] = sum_c W[m][c] * x[c][n] + bias
//   q -> Qt [bh][N][64] (n-major, pre-scaled by C^-0.5 * log2(e))
//   k -> Kt [bh][N][64] (n-major)
//   v -> Vc [bh][64][N] (c-major)
// ---------------------------------------------------------------------------
__global__ __launch_bounds__(256) void k_qkv(const u16* __restrict__ xt,
                                             const u16* __restrict__ wbf,
                                             const float* __restrict__ eb,
                                             u16* __restrict__ Qt,
                                             u16* __restrict__ Kt,
                                             u16* __restrict__ Vc) {
  int b = blockIdx.z;          // 4
  int mt = blockIdx.y;         // 6  (64-wide m tiles; 192 per head = 3 tiles)
  int nt = blockIdx.x;         // 64 (64-wide n tiles)
  int w = threadIdx.x >> 6, l = threadIdx.x & 63;
  int lr = l & 15, lg = l >> 4;
  int h = mt / 3, type = mt % 3;

  const u16* arow = xt + ((size_t)b * N_POS + nt*64 + w*16 + lr) * C_IN + lg*8;
  const u16* brow = wbf + ((size_t)(mt*64) + lr) * C_IN + lg*8;

  f32x4 acc[4] = {};
#pragma unroll
  for (int kk = 0; kk < 8; kk++) {
    bf16x8 a = *(const bf16x8*)(arow + kk*32);
#pragma unroll
    for (int mf = 0; mf < 4; mf++) {
      bf16x8 bf = *(const bf16x8*)(brow + (size_t)mf*16*C_IN + kk*32);
      acc[mf] = __builtin_amdgcn_mfma_f32_16x16x32_bf16(a, bf, acc[mf], 0, 0, 0);
    }
  }

  const float QSCALE = 0.0625f * 1.44269504088896f;  // C^-0.5 * log2(e)
  int bh = b * NH + h;
  int n0 = nt*64 + w*16 + lg*4;   // 4 consecutive rows (regs)
#pragma unroll
  for (int mf = 0; mf < 4; mf++) {
    int cl = mf*16 + lr;                        // channel within head [0,64)
    float bias = eb[h*192 + type*64 + cl];
    if (type == 0) {
      u16* q = Qt + (size_t)bh * N_POS * HC;
#pragma unroll
      for (int r = 0; r < 4; r++) q[(size_t)(n0+r)*HC + cl] = f2bf((acc[mf][r] + bias) * QSCALE);
    } else if (type == 1) {
      u16* kd = Kt + (size_t)bh * N_POS * HC;
#pragma unroll
      for (int r = 0; r < 4; r++) kd[(size_t)(n0+r)*HC + cl] = f2bf(acc[mf][r] + bias);
    } else {
      u16* vd = Vc + ((size_t)bh * HC + cl) * N_POS;
#pragma unroll
      for (int r = 0; r < 4; r++) vd[n0 + r] = f2bf(acc[mf][r] + bias);
    }
  }
}

// ---------------------------------------------------------------------------
// Kernel 2: flash attention, swapped-operand form. No LDS, no barriers.
//   S^T = mfma(A=K, B=Q):  lane holds S[m=lr][n = nf*16 + 4*lg + r]
//   softmax: per-lane partial + shfl_xor(16), shfl_xor(32); rm/rs per-lane
//   O^T = mfma(A=V^T, B=P) with slot map psi(lg,j)=4lg+(j&3)+16(j>>2)
//     -> P frag = straight cvt_pk of s regs (no shuffles);
//        V frag = two 8B contiguous loads from c-major Vc
//   O lane holds O[m=lr][c = cf*16 + 4*lg + r]
// ---------------------------------------------------------------------------
#define KVT 64
__global__ __launch_bounds__(256) void k_attn(const u16* __restrict__ Qt,
                                              const u16* __restrict__ Kt,
                                              const u16* __restrict__ Vc,
                                              u16* __restrict__ Ot) {
  int bh = blockIdx.y;            // 8
  int mt = blockIdx.x;            // 64 tiles of 64 query rows
  int b = bh >> 1, h = bh & 1;
  int w = threadIdx.x >> 6, l = threadIdx.x & 63;
  int lr = l & 15, lg = l >> 4;
  int m0 = mt*64 + w*16;

  // Q fragment (B operand of S^T): slot (lg,j) <- Q[m0+lr][kk*32+lg*8+j]
  const u16* qbase = Qt + ((size_t)bh * N_POS + m0 + lr) * HC + lg*8;
  bf16x8 qf0 = *(const bf16x8*)(qbase);
  bf16x8 qf1 = *(const bf16x8*)(qbase + 32);

  const u16* kbase = Kt + (size_t)bh * N_POS * HC + (size_t)lr * HC + lg*8;
  const u16* vbase = Vc + (size_t)bh * HC * N_POS + (size_t)lr * N_POS + lg*4;

  f32x4 o[4] = {};
  float rm = -1e30f, rs = 0.f;

  union PF { bf16x8 v; unsigned u[4]; };
  union VF { bf16x8 v; ushort4 h[2]; };

  for (int nt = 0; nt < N_POS / KVT; nt++) {
    // ---- S^T = K . Q^T  (64 n x 16 m per wave) ----
    f32x4 s[4];
#pragma unroll
    for (int nf = 0; nf < 4; nf++) {
      const u16* kp = kbase + (size_t)(nt*KVT + nf*16) * HC;
      bf16x8 k0 = *(const bf16x8*)kp;
      bf16x8 k1 = *(const bf16x8*)(kp + 32);
      f32x4 z = {};
      z = __builtin_amdgcn_mfma_f32_16x16x32_bf16(k0, qf0, z, 0, 0, 0);
      s[nf] = __builtin_amdgcn_mfma_f32_16x16x32_bf16(k1, qf1, z, 0, 0, 0);
    }

    // ---- online softmax: row m = lr is spread over the 4 lane-groups ----
    float mx = s[0][0];
#pragma unroll
    for (int nf = 0; nf < 4; nf++)
#pragma unroll
      for (int r = 0; r < 4; r++) mx = fmaxf(mx, s[nf][r]);
    mx = fmaxf(mx, __shfl_xor(mx, 16));
    mx = fmaxf(mx, __shfl_xor(mx, 32));
    float nm = fmaxf(rm, mx);
    float corr = EXP2(rm - nm);
    rm = nm;
    float ls = 0.f;
#pragma unroll
    for (int nf = 0; nf < 4; nf++)
#pragma unroll
      for (int r = 0; r < 4; r++) {
        float p = EXP2(s[nf][r] - nm);
        s[nf][r] = p;
        ls += p;
      }
    ls += __shfl_xor(ls, 16);
    ls += __shfl_xor(ls, 32);
    rs = rs * corr + ls;
#pragma unroll
    for (int cf = 0; cf < 4; cf++)
#pragma unroll
      for (int r = 0; r < 4; r++) o[cf][r] *= corr;

    // ---- O^T += V^T . P  ----
#pragma unroll
    for (int kk = 0; kk < 2; kk++) {
      PF pf;
      pf.u[0] = cvtpk_bf16(s[2*kk+0][0], s[2*kk+0][1]);
      pf.u[1] = cvtpk_bf16(s[2*kk+0][2], s[2*kk+0][3]);
      pf.u[2] = cvtpk_bf16(s[2*kk+1][0], s[2*kk+1][1]);
      pf.u[3] = cvtpk_bf16(s[2*kk+1][2], s[2*kk+1][3]);
#pragma unroll
      for (int cf = 0; cf < 4; cf++) {
        const u16* vp = vbase + (size_t)(cf*16) * N_POS + nt*KVT + kk*32;
        VF vf;
        vf.h[0] = *(const ushort4*)(vp);        // n = kk*32 + 4lg + 0..3
        vf.h[1] = *(const ushort4*)(vp + 16);   // n = kk*32 + 16 + 4lg + 0..3
        o[cf] = __builtin_amdgcn_mfma_f32_16x16x32_bf16(vf.v, pf.v, o[cf], 0, 0, 0);
      }
    }
  }

  // ---- normalize + write O_t [B][N][128] (d = h*64 + c) ----
  float rinv = 1.0f / rs;
  u16* ob = Ot + ((size_t)b * N_POS + m0 + lr) * (NH*HC) + h*HC;
#pragma unroll
  for (int cf = 0; cf < 4; cf++) {
    ushort4 wv;
    wv.x = f2bf(o[cf][0] * rinv);
    wv.y = f2bf(o[cf][1] * rinv);
    wv.z = f2bf(o[cf][2] * rinv);
    wv.w = f2bf(o[cf][3] * rinv);
    *(ushort4*)(ob + cf*16 + 4*lg) = wv;
  }
}

// ---------------------------------------------------------------------------
// Kernel 3: out[b][c][n] = sum_d Ot[n][d] * w2t[c][d] + out_b[c] + x[b][c][n]
// ---------------------------------------------------------------------------
__global__ __launch_bounds__(256) void k_out(const u16* __restrict__ Ot,
                                             const u16* __restrict__ w2t,
                                             const float* __restrict__ obias,
                                             const float* __restrict__ x,
                                             float* __restrict__ out) {
  int b = blockIdx.z;   // 4
  int ct = blockIdx.y;  // 4 (64-wide c tiles)
  int nt = blockIdx.x;  // 64
  int w = threadIdx.x >> 6, l = threadIdx.x & 63;
  int lr = l & 15, lg = l >> 4;

  const u16* arow = Ot + ((size_t)b * N_POS + nt*64 + w*16 + lr) * 128 + lg*8;
  const u16* brow = w2t + ((size_t)(ct*64) + lr) * 128 + lg*8;

  f32x4 acc[4] = {};
#pragma unroll
  for (int kk = 0; kk < 4; kk++) {
    bf16x8 a = *(const bf16x8*)(arow + kk*32);
#pragma unroll
    for (int cf = 0; cf < 4; cf++) {
      bf16x8 bf = *(const bf16x8*)(brow + (size_t)cf*16*128 + kk*32);
      acc[cf] = __builtin_amdgcn_mfma_f32_16x16x32_bf16(a, bf, acc[cf], 0, 0, 0);
    }
  }

  int n0 = nt*64 + w*16 + lg*4;
#pragma unroll
  for (int cf = 0; cf < 4; cf++) {
    int c = ct*64 + cf*16 + lr;
    float bias = obias[c];
    const float* xp = x + ((size_t)b * C_IN + c) * N_POS + n0;
    float* op = out + ((size_t)b * C_IN + c) * N_POS + n0;
    f32x4 xv = *(const f32x4*)xp;
    f32x4 rv;
#pragma unroll
    for (int i = 0; i < 4; i++) rv[i] = acc[cf][i] + bias + xv[i];
    *(f32x4*)op = rv;
  }
}

// ---------------------------------------------------------------------------
extern "C" void kernel_launch(void* const* d_in, const int* in_sizes, int n_in,
                              void* d_out, int out_size, void* d_ws, size_t ws_size,
                              hipStream_t stream) {
  const float* x  = (const float*)d_in[0];   // [4,256,64,64]
  const float* ew = (const float*)d_in[1];   // [2,192,256]
  const float* eb = (const float*)d_in[2];   // [2,192]
  const float* ow = (const float*)d_in[3];   // [128,256]
  const float* ob = (const float*)d_in[4];   // [256]
  float* out = (float*)d_out;

  char* ws = (char*)d_ws;
  u16* xt  = (u16*)(ws + 0);          //  8,388,608 B  x_t  [B][N][C]
  u16* wbf = (u16*)(ws + 8388608);    //    196,608 B  embed_w bf16 [384][256]
  u16* w2t = (u16*)(ws + 8585216);    //     65,536 B  out_w^T bf16 [256][128]
  u16* Qt  = (u16*)(ws + 8650752);    //  4,194,304 B  [8][4096][64]
  u16* Kt  = (u16*)(ws + 12845056);   //  4,194,304 B  [8][4096][64]
  u16* Vc  = (u16*)(ws + 17039360);   //  4,194,304 B  [8][64][4096]
  u16* Ot  = (u16*)(ws + 21233664);   //  4,194,304 B  [B][N][128]

  hipLaunchKernelGGL(k_prep_x, dim3(128, 8, 4), dim3(32, 8), 0, stream, x, xt);
  hipLaunchKernelGGL(k_prep_w, dim3(384), dim3(256), 0, stream, ew, ow, wbf, w2t);
  hipLaunchKernelGGL(k_qkv,  dim3(64, 6, 4), dim3(256), 0, stream, xt, wbf, eb, Qt, Kt, Vc);
  hipLaunchKernelGGL(k_attn, dim3(64, 8),    dim3(256), 0, stream, Qt, Kt, Vc, Ot);
  hipLaunchKernelGGL(k_out,  dim3(64, 4, 4), dim3(256), 0, stream, Ot, w2t, ob, x, out);
}

// Round 3
// 212.534 us; speedup vs baseline: 1.8434x; 1.8434x over previous
//
#include <hip/hip_runtime.h>

// Problem constants
#define B_SZ  4
#define C_IN  256
#define N_POS 4096     // H*W = 64*64
#define NH    2
#define HC    64       // hidden per head

typedef __attribute__((ext_vector_type(8))) __bf16 bf16x8;
typedef __attribute__((ext_vector_type(4))) float  f32x4;
typedef unsigned short u16;

__device__ __forceinline__ u16 f2bf(float f) {
  unsigned u = __float_as_uint(f);
  u = u + 0x7FFF + ((u >> 16) & 1);   // round-nearest-even
  return (u16)(u >> 16);
}

#if __has_builtin(__builtin_amdgcn_exp2f)
  #define EXP2(x) __builtin_amdgcn_exp2f(x)
#else
  #define EXP2(x) exp2f(x)
#endif

// packed f32x2 -> bf16x2 (RNE), low half = src0
__device__ __forceinline__ unsigned cvtpk_bf16(float lo, float hi) {
  unsigned r;
  asm("v_cvt_pk_bf16_f32 %0, %1, %2" : "=v"(r) : "v"(lo), "v"(hi));
  return r;
}

// ---------------------------------------------------------------------------
// Kernel 0a: x [B][C][N] fp32  ->  x_t [B][N][C] bf16  (transposed cast)
// ---------------------------------------------------------------------------
__global__ __launch_bounds__(256) void k_prep_x(const float* __restrict__ x,
                                                u16* __restrict__ xt) {
  __shared__ float tile[32][33];
  int b = blockIdx.z, c0 = blockIdx.y * 32, n0 = blockIdx.x * 32;
  int tx = threadIdx.x, ty = threadIdx.y;   // (32, 8)
  const float* src = x + ((size_t)b * C_IN + c0) * N_POS + n0;
#pragma unroll
  for (int i = 0; i < 4; i++) tile[ty + 8*i][tx] = src[(size_t)(ty + 8*i) * N_POS + tx];
  __syncthreads();
  u16* dst = xt + ((size_t)b * N_POS + n0) * C_IN + c0;
#pragma unroll
  for (int i = 0; i < 4; i++) dst[(size_t)(ty + 8*i) * C_IN + tx] = f2bf(tile[tx][ty + 8*i]);
}

// ---------------------------------------------------------------------------
// Kernel 0b: cast embed_w -> wbf [384][256] bf16 ; transpose out_w -> w2t [256][128] bf16
// ---------------------------------------------------------------------------
__global__ __launch_bounds__(256) void k_prep_w(const float* __restrict__ ew,
                                                const float* __restrict__ ow,
                                                u16* __restrict__ wbf,
                                                u16* __restrict__ w2t) {
  int i = blockIdx.x * 256 + threadIdx.x;
  if (i < 384 * 256) wbf[i] = f2bf(ew[i]);
  if (i < 128 * 256) {
    int d = i >> 8, c = i & 255;              // out_w[d][c]
    w2t[c * 128 + d] = f2bf(ow[i]);
  }
}

// ---------------------------------------------------------------------------
// Kernel 1: QKV projection.
//   q -> Qt [bh][N][64] (n-major, pre-scaled by C^-0.5 * log2(e))
//   k -> Kt [bh][N][64] (n-major)
//   v -> Vs [bh][nt(64)][kk(2)][lg(4)][c(64)][8]  (PV-fragment order:
//        elem e at (nt,kk,lg,c) holds V[c][n = nt*64 + kk*32 + 4*lg + (e&3) + 16*(e>>2)])
// ---------------------------------------------------------------------------
__global__ __launch_bounds__(256) void k_qkv(const u16* __restrict__ xt,
                                             const u16* __restrict__ wbf,
                                             const float* __restrict__ eb,
                                             u16* __restrict__ Qt,
                                             u16* __restrict__ Kt,
                                             u16* __restrict__ Vs) {
  int b = blockIdx.z;          // 4
  int mt = blockIdx.y;         // 6
  int nt = blockIdx.x;         // 64
  int w = threadIdx.x >> 6, l = threadIdx.x & 63;
  int lr = l & 15, lg = l >> 4;
  int h = mt / 3, type = mt % 3;

  const u16* arow = xt + ((size_t)b * N_POS + nt*64 + w*16 + lr) * C_IN + lg*8;
  const u16* brow = wbf + ((size_t)(mt*64) + lr) * C_IN + lg*8;

  f32x4 acc[4] = {};
#pragma unroll
  for (int kk = 0; kk < 8; kk++) {
    bf16x8 a = *(const bf16x8*)(arow + kk*32);
#pragma unroll
    for (int mf = 0; mf < 4; mf++) {
      bf16x8 bf = *(const bf16x8*)(brow + (size_t)mf*16*C_IN + kk*32);
      acc[mf] = __builtin_amdgcn_mfma_f32_16x16x32_bf16(a, bf, acc[mf], 0, 0, 0);
    }
  }

  const float QSCALE = 0.0625f * 1.44269504088896f;  // C^-0.5 * log2(e)
  int bh = b * NH + h;
  int n0 = nt*64 + w*16 + lg*4;   // 4 consecutive n (regs)
#pragma unroll
  for (int mf = 0; mf < 4; mf++) {
    int cl = mf*16 + lr;                        // channel within head [0,64)
    float bias = eb[h*192 + type*64 + cl];
    if (type == 0) {
      u16* q = Qt + (size_t)bh * N_POS * HC;
#pragma unroll
      for (int r = 0; r < 4; r++) q[(size_t)(n0+r)*HC + cl] = f2bf((acc[mf][r] + bias) * QSCALE);
    } else if (type == 1) {
      u16* kd = Kt + (size_t)bh * N_POS * HC;
#pragma unroll
      for (int r = 0; r < 4; r++) kd[(size_t)(n0+r)*HC + cl] = f2bf(acc[mf][r] + bias);
    } else {
      // permuted V store: kk=w>>1, group=lg, e = 4*(w&1) + r
      u16* vd = Vs + (size_t)bh * (N_POS * HC);
      size_t idx = ((((size_t)nt*2 + (w>>1))*4 + lg)*64 + cl)*8 + 4*(w&1);
      ushort4 pk;
      pk.x = f2bf(acc[mf][0] + bias);
      pk.y = f2bf(acc[mf][1] + bias);
      pk.z = f2bf(acc[mf][2] + bias);
      pk.w = f2bf(acc[mf][3] + bias);
      *(ushort4*)(vd + idx) = pk;
    }
  }
}

// ---------------------------------------------------------------------------
// Kernel 2: flash attention, swapped-operand, no LDS/barriers, reg double-buffer.
// ---------------------------------------------------------------------------
struct KB { bf16x8 k[4][2]; };
struct VB { bf16x8 v[2][4]; };

__device__ __forceinline__ void load_kb(KB& kb, const u16* kbase, int nt) {
#pragma unroll
  for (int nf = 0; nf < 4; nf++) {
    const u16* kp = kbase + (size_t)(nt*64 + nf*16) * HC;
    kb.k[nf][0] = *(const bf16x8*)kp;
    kb.k[nf][1] = *(const bf16x8*)(kp + 32);
  }
}

__device__ __forceinline__ void load_vb(VB& vb, const u16* vbase, int nt) {
#pragma unroll
  for (int kk = 0; kk < 2; kk++)
#pragma unroll
    for (int cf = 0; cf < 4; cf++)
      vb.v[kk][cf] = *(const bf16x8*)(vbase + (size_t)(nt*2 + kk)*2048 + cf*128);
}

__device__ __forceinline__ void attn_step(const KB& kb, const VB& vb,
                                          bf16x8 qf0, bf16x8 qf1,
                                          f32x4 (&o)[4], float& rm, float& rs) {
  union PF { bf16x8 v; unsigned u[4]; };
  // ---- S^T = K . Q^T ----
  f32x4 s[4];
#pragma unroll
  for (int nf = 0; nf < 4; nf++) {
    f32x4 z = {};
    z = __builtin_amdgcn_mfma_f32_16x16x32_bf16(kb.k[nf][0], qf0, z, 0, 0, 0);
    s[nf] = __builtin_amdgcn_mfma_f32_16x16x32_bf16(kb.k[nf][1], qf1, z, 0, 0, 0);
  }
  // ---- online softmax (row m = lane&15, spread over 4 lane-groups) ----
  float mx = s[0][0];
#pragma unroll
  for (int nf = 0; nf < 4; nf++)
#pragma unroll
    for (int r = 0; r < 4; r++) mx = fmaxf(mx, s[nf][r]);
  mx = fmaxf(mx, __shfl_xor(mx, 16));
  mx = fmaxf(mx, __shfl_xor(mx, 32));
  float nm = fmaxf(rm, mx);
  float corr = EXP2(rm - nm);
  rm = nm;
  float ls = 0.f;
#pragma unroll
  for (int nf = 0; nf < 4; nf++)
#pragma unroll
    for (int r = 0; r < 4; r++) {
      float p = EXP2(s[nf][r] - nm);
      s[nf][r] = p;
      ls += p;
    }
  ls += __shfl_xor(ls, 16);
  ls += __shfl_xor(ls, 32);
  rs = rs * corr + ls;
#pragma unroll
  for (int cf = 0; cf < 4; cf++)
#pragma unroll
    for (int r = 0; r < 4; r++) o[cf][r] *= corr;
  // ---- O^T += V^T . P ----
#pragma unroll
  for (int kk = 0; kk < 2; kk++) {
    PF pf;
    pf.u[0] = cvtpk_bf16(s[2*kk+0][0], s[2*kk+0][1]);
    pf.u[1] = cvtpk_bf16(s[2*kk+0][2], s[2*kk+0][3]);
    pf.u[2] = cvtpk_bf16(s[2*kk+1][0], s[2*kk+1][1]);
    pf.u[3] = cvtpk_bf16(s[2*kk+1][2], s[2*kk+1][3]);
#pragma unroll
    for (int cf = 0; cf < 4; cf++)
      o[cf] = __builtin_amdgcn_mfma_f32_16x16x32_bf16(vb.v[kk][cf], pf.v, o[cf], 0, 0, 0);
  }
}

__global__ __launch_bounds__(256) void k_attn(const u16* __restrict__ Qt,
                                              const u16* __restrict__ Kt,
                                              const u16* __restrict__ Vs,
                                              u16* __restrict__ Ot) {
  int id = blockIdx.x;            // 512
  int bh = id & 7;                // XCD-swizzle: one (b,h) per XCD
  int mt = id >> 3;               // 64 q-tiles
  int b = bh >> 1, h = bh & 1;
  int w = threadIdx.x >> 6, l = threadIdx.x & 63;
  int lr = l & 15, lg = l >> 4;
  int m0 = mt*64 + w*16;

  const u16* qbase = Qt + ((size_t)bh * N_POS + m0 + lr) * HC + lg*8;
  bf16x8 qf0 = *(const bf16x8*)(qbase);
  bf16x8 qf1 = *(const bf16x8*)(qbase + 32);

  const u16* kbase = Kt + (size_t)bh * N_POS * HC + (size_t)lr * HC + lg*8;
  const u16* vbase = Vs + (size_t)bh * (N_POS * HC) + (size_t)lg*512 + (size_t)lr*8;

  f32x4 o[4] = {};
  float rm = -1e30f, rs = 0.f;

  KB kA, kB; VB vA, vB;
  load_kb(kA, kbase, 0); load_vb(vA, vbase, 0);

  for (int nt = 0; nt < N_POS / 64; nt += 2) {
    load_kb(kB, kbase, nt + 1);
    load_vb(vB, vbase, nt + 1);
    attn_step(kA, vA, qf0, qf1, o, rm, rs);
    load_kb(kA, kbase, nt + 2);   // at nt=62 reads tile 64: valid ws memory, unused
    load_vb(vA, vbase, nt + 2);
    attn_step(kB, vB, qf0, qf1, o, rm, rs);
  }

  // ---- normalize + write O_t [B][N][128] (d = h*64 + c) ----
  float rinv = 1.0f / rs;
  u16* ob = Ot + ((size_t)b * N_POS + m0 + lr) * (NH*HC) + h*HC;
#pragma unroll
  for (int cf = 0; cf < 4; cf++) {
    ushort4 wv;
    wv.x = f2bf(o[cf][0] * rinv);
    wv.y = f2bf(o[cf][1] * rinv);
    wv.z = f2bf(o[cf][2] * rinv);
    wv.w = f2bf(o[cf][3] * rinv);
    *(ushort4*)(ob + cf*16 + 4*lg) = wv;
  }
}

// ---------------------------------------------------------------------------
// Kernel 3: out[b][c][n] = sum_d Ot[n][d] * w2t[c][d] + out_b[c] + x[b][c][n]
// ---------------------------------------------------------------------------
__global__ __launch_bounds__(256) void k_out(const u16* __restrict__ Ot,
                                             const u16* __restrict__ w2t,
                                             const float* __restrict__ obias,
                                             const float* __restrict__ x,
                                             float* __restrict__ out) {
  int b = blockIdx.z;   // 4
  int ct = blockIdx.y;  // 4
  int nt = blockIdx.x;  // 64
  int w = threadIdx.x >> 6, l = threadIdx.x & 63;
  int lr = l & 15, lg = l >> 4;

  const u16* arow = Ot + ((size_t)b * N_POS + nt*64 + w*16 + lr) * 128 + lg*8;
  const u16* brow = w2t + ((size_t)(ct*64) + lr) * 128 + lg*8;

  f32x4 acc[4] = {};
#pragma unroll
  for (int kk = 0; kk < 4; kk++) {
    bf16x8 a = *(const bf16x8*)(arow + kk*32);
#pragma unroll
    for (int cf = 0; cf < 4; cf++) {
      bf16x8 bf = *(const bf16x8*)(brow + (size_t)cf*16*128 + kk*32);
      acc[cf] = __builtin_amdgcn_mfma_f32_16x16x32_bf16(a, bf, acc[cf], 0, 0, 0);
    }
  }

  int n0 = nt*64 + w*16 + lg*4;
#pragma unroll
  for (int cf = 0; cf < 4; cf++) {
    int c = ct*64 + cf*16 + lr;
    float bias = obias[c];
    const float* xp = x + ((size_t)b * C_IN + c) * N_POS + n0;
    float* op = out + ((size_t)b * C_IN + c) * N_POS + n0;
    f32x4 xv = *(const f32x4*)xp;
    f32x4 rv;
#pragma unroll
    for (int i = 0; i < 4; i++) rv[i] = acc[cf][i] + bias + xv[i];
    *(f32x4*)op = rv;
  }
}

// ---------------------------------------------------------------------------
extern "C" void kernel_launch(void* const* d_in, const int* in_sizes, int n_in,
                              void* d_out, int out_size, void* d_ws, size_t ws_size,
                              hipStream_t stream) {
  const float* x  = (const float*)d_in[0];   // [4,256,64,64]
  const float* ew = (const float*)d_in[1];   // [2,192,256]
  const float* eb = (const float*)d_in[2];   // [2,192]
  const float* ow = (const float*)d_in[3];   // [128,256]
  const float* ob = (const float*)d_in[4];   // [256]
  float* out = (float*)d_out;

  char* ws = (char*)d_ws;
  u16* xt  = (u16*)(ws + 0);          //  8,388,608 B  x_t  [B][N][C]
  u16* wbf = (u16*)(ws + 8388608);    //    196,608 B  embed_w bf16 [384][256]
  u16* w2t = (u16*)(ws + 8585216);    //     65,536 B  out_w^T bf16 [256][128]
  u16* Qt  = (u16*)(ws + 8650752);    //  4,194,304 B  [8][4096][64]
  u16* Kt  = (u16*)(ws + 12845056);   //  4,194,304 B  [8][4096][64]
  u16* Vs  = (u16*)(ws + 17039360);   //  4,194,304 B  permuted V
  u16* Ot  = (u16*)(ws + 21233664);   //  4,194,304 B  [B][N][128]

  hipLaunchKernelGGL(k_prep_x, dim3(128, 8, 4), dim3(32, 8), 0, stream, x, xt);
  hipLaunchKernelGGL(k_prep_w, dim3(384), dim3(256), 0, stream, ew, ow, wbf, w2t);
  hipLaunchKernelGGL(k_qkv,  dim3(64, 6, 4), dim3(256), 0, stream, xt, wbf, eb, Qt, Kt, Vs);
  hipLaunchKernelGGL(k_attn, dim3(512),      dim3(256), 0, stream, Qt, Kt, Vs, Ot);
  hipLaunchKernelGGL(k_out,  dim3(64, 4, 4), dim3(256), 0, stream, Ot, w2t, ob, x, out);
}